// Round 13
// baseline (111.565 us; speedup 1.0000x reference)
//
#include <hip/hip_runtime.h>
#include <hip/hip_bf16.h>
#include <math.h>

// Router: logits = X @ W^T + b ; top-2 over 64 experts; softmax over the 2; rest 0.
// X: [32768,1024] f32, W: [64,1024] f32, b: [64] f32, Out: [32768,64] f32.
//
// MFMA path: exact bf16 hi/lo split, 3-term product (hh + hl + lh).
//
// Round-13: same router core as round 12 (best measured: cooperative
// row-contiguous staging, LDS-shared W, 8 waves/CU, counted vmcnt(8) +
// s_barrier). Change: near-tie rescue is INLINED into the epilogue -- when a
// third logit lies within TAU of v2, the token's 16 lanes recompute its 64
// logits in exact fp32 (same summation order as the old rescue kernel) and
// redo the top-2. Deletes memset + atomics + flag buffers + the 512-block
// rescue dispatch: graph = 2 dispatches (pack_w, router). ~0.3% of tokens
// take the slow path (~1us each, amortized across 2048 waves).
//
// A/B k-mapping: element j of lane l covers k = (l>>4)*8 + j, identical for A
// (in-register split) and B (pack_w) -> permutation-safe.
// C/D layout (m89-verified): col = lane&15, row = (lane>>4)*4 + reg.
//
// Requires ws_size >= 512 KB (Whi @256K, Wlo @384K).

typedef __attribute__((ext_vector_type(8))) short bf16x8;
typedef __attribute__((ext_vector_type(4))) float f32x4;

#define TOKENS 32768
#define DDIM   1024
#define TAU    1e-3f

#define WS_WHI_OFF   262144
#define WS_WLO_OFF   (262144 + 131072)

#define AS1 __attribute__((address_space(1)))
#define AS3 __attribute__((address_space(3)))

union FragU { bf16x8 v; unsigned int u[4]; };
union FragU4 { bf16x8 v; uint4 q; };

__device__ inline unsigned int pk_bf16(float a, float b) {
    float2 f; f.x = a; f.y = b;
    __hip_bfloat162 h = __float22bfloat162_rn(f);
    union { __hip_bfloat162 h2; unsigned int u; } cv; cv.h2 = h;
    return cv.u;
}
__device__ inline float2 bf2f2(unsigned int u) {
    union { __hip_bfloat162 h2; unsigned int uu; } cv; cv.uu = u;
    return __bfloat1622float2(cv.h2);
}
__device__ inline void merge2(float& v1, int& i1, float& v2, int& i2,
                              float o1, int oi1, float o2, int oi2) {
    const bool b1 = (o1 > v1) || (o1 == v1 && oi1 < i1);
    if (b1) {
        const bool b2 = (v1 > o2) || (v1 == o2 && i1 < oi2);
        v2 = b2 ? v1 : o2;  i2 = b2 ? i1 : oi2;
        v1 = o1;            i1 = oi1;
    } else {
        const bool b2 = (o1 > v2) || (o1 == v2 && oi1 < i2);
        if (b2) { v2 = o1; i2 = oi1; }
    }
}

// top-2 of v[4] (experts n*16+rl) + 16-lane butterfly merge.
__device__ inline void top2_16(const float v[4], int rl,
                               float& v1, int& i1, float& v2, int& i2) {
    v1 = -INFINITY; v2 = -INFINITY;
    i1 = 0x7fffffff; i2 = 0x7fffffff;
    #pragma unroll
    for (int n = 0; n < 4; ++n) {
        const float val = v[n];
        const int   e   = n * 16 + rl;
        if (val > v1 || (val == v1 && e < i1)) { v2 = v1; i2 = i1; v1 = val; i1 = e; }
        else if (val > v2 || (val == v2 && e < i2)) { v2 = val; i2 = e; }
    }
    #pragma unroll
    for (int st = 1; st <= 8; st <<= 1) {
        const float o1 = __shfl_xor(v1, st); const int oi1 = __shfl_xor(i1, st);
        const float o2 = __shfl_xor(v2, st); const int oi2 = __shfl_xor(i2, st);
        merge2(v1, i1, v2, i2, o1, oi1, o2, oi2);
    }
}

// ---- kernel 1: pack W into fragment-ordered bf16 hi/lo ----
__launch_bounds__(256)
__global__ void pack_w_kernel(const float* __restrict__ W,
                              unsigned int* __restrict__ Whi,
                              unsigned int* __restrict__ Wlo) {
    const int idx = blockIdx.x * 256 + threadIdx.x;     // 0..8191 = (s,n,l)
    const int l = idx & 63, n = (idx >> 6) & 3, s = idx >> 8;
    const int e  = n * 16 + (l & 15);
    const int k0 = s * 32 + (l >> 4) * 8;
    const float* p = W + e * DDIM + k0;
    const float4 a = *(const float4*)p;
    const float4 b = *(const float4*)(p + 4);
    const float f[8] = {a.x, a.y, a.z, a.w, b.x, b.y, b.z, b.w};
    unsigned int hu[4], lu[4];
    #pragma unroll
    for (int j = 0; j < 4; ++j) {
        const float x0 = f[2 * j], x1 = f[2 * j + 1];
        const unsigned int h = pk_bf16(x0, x1);
        const float2 hf = bf2f2(h);
        hu[j] = h;
        lu[j] = pk_bf16(x0 - hf.x, x1 - hf.y);
    }
    uint4 hv; hv.x = hu[0]; hv.y = hu[1]; hv.z = hu[2]; hv.w = hu[3];
    uint4 lv; lv.x = lu[0]; lv.y = lu[1]; lv.z = lu[2]; lv.w = lu[3];
    *(uint4*)(Whi + (size_t)idx * 4) = hv;
    *(uint4*)(Wlo + (size_t)idx * 4) = lv;
}

// ---- kernel 2: main MFMA router (cooperative phases, LDS-shared W,
//                inline fp32 near-tie rescue) ----
__launch_bounds__(256, 2)
__global__ void router_mfma(const float* __restrict__ X,
                            const float* __restrict__ Wf,
                            const unsigned int* __restrict__ Whi,
                            const unsigned int* __restrict__ Wlo,
                            const float* __restrict__ Bv,
                            float* __restrict__ Out) {
    // [0,32K): X dbuf (2 x 64 rows x 256B). [32K,64K): W dbuf (2 x (hi 8K + lo 8K)).
    __shared__ __align__(16) char smem[65536];

    const int tid  = threadIdx.x;
    const int w    = tid >> 6;
    const int lane = tid & 63;
    const int rl   = lane & 15;      // A-row (token in tile) / C-col
    const int kg   = lane >> 4;      // k-group
    const int dr   = lane >> 4;      // staging row-within-group
    const int tokBase = blockIdx.x * 64;

    // --- X staging sources (pre-swizzled chunk; dest linear) ---
    const float* xsE = X + (size_t)(tokBase + w * 16 + dr) * DDIM
                         + (((lane & 15) ^ dr) * 4);
    const float* xsO = X + (size_t)(tokBase + w * 16 + dr) * DDIM
                         + (((lane & 15) ^ (dr ^ 4)) * 4);
    const unsigned int* whs = Whi + lane * 4;   // +lane*16B
    const unsigned int* wls = Wlo + lane * 4;

    // --- A-frag swizzled ds_read offsets ---
    const int r7     = rl & 7;
    const int rowoff = w * 4096 + rl * 256;
    const int q0     = ((kg * 2 + 0) ^ r7) * 16;
    const int q1     = ((kg * 2 + 1) ^ r7) * 16;
    const int wlds   = lane * 16;

    f32x4 acc[4] = {f32x4{0,0,0,0}, f32x4{0,0,0,0}, f32x4{0,0,0,0}, f32x4{0,0,0,0}};

#define DMA16(gp, lp) __builtin_amdgcn_global_load_lds((AS1 const void*)(gp), \
                                                       (AS3 void*)(lp), 16, 0, 0)
#define WAITVM(N) asm volatile("s_waitcnt vmcnt(" #N ")" ::: "memory")
#define SB() __builtin_amdgcn_sched_barrier(0)

    auto ISSUE = [&](int p, const float* xE, const float* xO,
                     const unsigned int* wh, const unsigned int* wl) {
        char* xb = smem + ((p & 1) ? 16384 : 0) + w * 4096;
        DMA16(xE,         xb);
        DMA16(xO + 4096,  xb + 1024);
        DMA16(xE + 8192,  xb + 2048);
        DMA16(xO + 12288, xb + 3072);
        char* wb = smem + 32768 + ((p & 1) ? 16384 : 0);
        DMA16(wh + (w * 2 + 0) * 256, wb + (w * 2 + 0) * 1024);
        DMA16(wh + (w * 2 + 1) * 256, wb + (w * 2 + 1) * 1024);
        DMA16(wl + (w * 2 + 0) * 256, wb + 8192 + (w * 2 + 0) * 1024);
        DMA16(wl + (w * 2 + 1) * 256, wb + 8192 + (w * 2 + 1) * 1024);
    };

    auto CONSUME = [&](int p) {
        const char* xb = smem + ((p & 1) ? 16384 : 0);
        const char* wb = smem + 32768 + ((p & 1) ? 16384 : 0);
        #pragma unroll
        for (int sl = 0; sl < 2; ++sl) {
            const float4 x0 = *(const float4*)(xb + rowoff + sl * 128 + q0);
            const float4 x1 = *(const float4*)(xb + rowoff + sl * 128 + q1);
            FragU4 bh[4], bl[4];
            #pragma unroll
            for (int n = 0; n < 4; ++n) {
                bh[n].q = *(const uint4*)(wb + (sl * 4 + n) * 1024 + wlds);
                bl[n].q = *(const uint4*)(wb + 8192 + (sl * 4 + n) * 1024 + wlds);
            }
            FragU ah, al;
            const float fx[8] = {x0.x, x0.y, x0.z, x0.w, x1.x, x1.y, x1.z, x1.w};
            #pragma unroll
            for (int j = 0; j < 4; ++j) {
                const unsigned int h = pk_bf16(fx[2 * j], fx[2 * j + 1]);
                const float2 hf = bf2f2(h);
                ah.u[j] = h;
                al.u[j] = pk_bf16(fx[2 * j] - hf.x, fx[2 * j + 1] - hf.y);
            }
            #pragma unroll
            for (int n = 0; n < 4; ++n) {
                acc[n] = __builtin_amdgcn_mfma_f32_16x16x32_bf16(ah.v, bh[n].v, acc[n], 0, 0, 0);
                acc[n] = __builtin_amdgcn_mfma_f32_16x16x32_bf16(ah.v, bl[n].v, acc[n], 0, 0, 0);
                acc[n] = __builtin_amdgcn_mfma_f32_16x16x32_bf16(al.v, bh[n].v, acc[n], 0, 0, 0);
            }
        }
    };

    // Prologue: phases 0 and 1 in flight (8 DMA each per wave).
    ISSUE(0, xsE, xsO, whs, wls);
    ISSUE(1, xsE + 64, xsO + 64, whs + 2048, wls + 2048);
    const float* xE2 = xsE + 128;
    const float* xO2 = xsO + 128;
    const unsigned int* wh2 = whs + 4096;
    const unsigned int* wl2 = wls + 4096;

    #pragma unroll 1
    for (int p = 0; p < 15; ++p) {
        WAITVM(8);                       // own phase-p DMAs done; p+1 in flight
        __builtin_amdgcn_s_barrier();    // -> block-wide: phase p fully in LDS
        SB();
        CONSUME(p);
        SB();
        __builtin_amdgcn_s_barrier();    // all reads of slot (p&1) done
        if (p < 14) {
            ISSUE(p + 2, xE2, xO2, wh2, wl2);
            xE2 += 64; xO2 += 64; wh2 += 2048; wl2 += 2048;
        }
    }
    WAITVM(0);
    __builtin_amdgcn_s_barrier();
    SB();
    CONSUME(15);

#undef DMA16
#undef WAITVM
#undef SB

    // ---- wave-private epilogue: bias + top-2 (+ inline fp32 rescue) + write ----
    float bv[4];
    #pragma unroll
    for (int n = 0; n < 4; ++n) bv[n] = Bv[n * 16 + rl];

    #pragma unroll
    for (int r = 0; r < 4; ++r) {
        float v[4];
        #pragma unroll
        for (int n = 0; n < 4; ++n) v[n] = acc[n][r] + bv[n];

        float v1, v2; int i1, i2;
        top2_16(v, rl, v1, i1, v2, i2);

        // near-tie: any 3rd logit within TAU of v2? (cnt counts v1,v2 too)
        int cnt = 0;
        #pragma unroll
        for (int n = 0; n < 4; ++n) cnt += (v[n] > v2 - TAU) ? 1 : 0;
        cnt += __shfl_xor(cnt, 1);
        cnt += __shfl_xor(cnt, 2);
        cnt += __shfl_xor(cnt, 4);
        cnt += __shfl_xor(cnt, 8);

        const int T = tokBase + w * 16 + kg * 4 + r;

        if (cnt > 2) {
            // Inline exact fp32 recompute for token T (rare: ~0.3% of tokens).
            // Same float4 summation order as the old rescue kernel.
            const float* xr = X + (size_t)T * DDIM;
            float a0 = 0.f, a1 = 0.f, a2 = 0.f, a3 = 0.f;
            const float* w0 = Wf + (size_t)(0 * 16 + rl) * DDIM;
            const float* w1 = Wf + (size_t)(1 * 16 + rl) * DDIM;
            const float* w2 = Wf + (size_t)(2 * 16 + rl) * DDIM;
            const float* w3 = Wf + (size_t)(3 * 16 + rl) * DDIM;
            #pragma unroll 4
            for (int d = 0; d < DDIM; d += 4) {
                const float4 xv = *(const float4*)(xr + d);
                const float4 a = *(const float4*)(w0 + d);
                const float4 b = *(const float4*)(w1 + d);
                const float4 c = *(const float4*)(w2 + d);
                const float4 e = *(const float4*)(w3 + d);
                a0 = fmaf(xv.x, a.x, a0); a0 = fmaf(xv.y, a.y, a0);
                a0 = fmaf(xv.z, a.z, a0); a0 = fmaf(xv.w, a.w, a0);
                a1 = fmaf(xv.x, b.x, a1); a1 = fmaf(xv.y, b.y, a1);
                a1 = fmaf(xv.z, b.z, a1); a1 = fmaf(xv.w, b.w, a1);
                a2 = fmaf(xv.x, c.x, a2); a2 = fmaf(xv.y, c.y, a2);
                a2 = fmaf(xv.z, c.z, a2); a2 = fmaf(xv.w, c.w, a2);
                a3 = fmaf(xv.x, e.x, a3); a3 = fmaf(xv.y, e.y, a3);
                a3 = fmaf(xv.z, e.z, a3); a3 = fmaf(xv.w, e.w, a3);
            }
            v[0] = a0 + bv[0]; v[1] = a1 + bv[1];
            v[2] = a2 + bv[2]; v[3] = a3 + bv[3];
            top2_16(v, rl, v1, i1, v2, i2);
        }

        const float ex = expf(v2 - v1);      // <= 1
        const float w1_ = 1.f / (1.f + ex);
        const float w2_ = ex * w1_;
        const int e0 = rl * 4;
        float4 o;
        o.x = (e0 + 0 == i1) ? w1_ : ((e0 + 0 == i2) ? w2_ : 0.f);
        o.y = (e0 + 1 == i1) ? w1_ : ((e0 + 1 == i2) ? w2_ : 0.f);
        o.z = (e0 + 2 == i1) ? w1_ : ((e0 + 2 == i2) ? w2_ : 0.f);
        o.w = (e0 + 3 == i1) ? w1_ : ((e0 + 3 == i2) ? w2_ : 0.f);
        *(float4*)(Out + (size_t)T * 64 + e0) = o;
    }
}

extern "C" void kernel_launch(void* const* d_in, const int* in_sizes, int n_in,
                              void* d_out, int out_size, void* d_ws, size_t ws_size,
                              hipStream_t stream) {
    const float* X  = (const float*)d_in[0];   // [32768, 1024]
    const float* W  = (const float*)d_in[1];   // [64, 1024]
    const float* Bv = (const float*)d_in[2];   // [64]
    float* Out = (float*)d_out;                // [32768, 64]

    unsigned char* ws = (unsigned char*)d_ws;
    unsigned int* Whi  = (unsigned int*)(ws + WS_WHI_OFF);
    unsigned int* Wlo  = (unsigned int*)(ws + WS_WLO_OFF);

    hipLaunchKernelGGL(pack_w_kernel, dim3(32), dim3(256), 0, stream, W, Whi, Wlo);
    hipLaunchKernelGGL(router_mfma, dim3(TOKENS / 64), dim3(256), 0, stream,
                       X, W, Whi, Wlo, Bv, Out);
}

// Round 14
// 79.475 us; speedup vs baseline: 1.4038x; 1.4038x over previous
//
#include <hip/hip_runtime.h>
#include <hip/hip_bf16.h>
#include <math.h>

// Router: logits = X @ W^T + b ; top-2 over 64 experts; softmax over the 2; rest 0.
// X: [32768,1024] f32, W: [64,1024] f32, b: [64] f32, Out: [32768,64] f32.
//
// MFMA path: exact bf16 hi/lo split, 3-term product (hh + hl + lh). Near-tie
// tokens (3rd logit within TAU of v2) recomputed exactly by rescue kernel.
//
// Round-14: REVERT to round-12's router core (best measured, 67.6us total).
// Round-13's inline-rescue experiment regressed 2x: the exec-masked fp32 loop
// in the epilogue + co-compiled register pressure (VGPR 88) perturbed the main
// loop (occupancy 25->10.7%, dur 2x at identical FETCH). Separate rescue kernel
// restored. Aux trims only:
//   (1) memset dispatch deleted -- pack_w block0/thread0 zeroes flagCnt
//       (same-stream ordering; re-zeroed every graph replay -> deterministic).
//   (2) rescue grid 512 -> 128 blocks (n ~ 100 flagged tokens).
// Graph = 3 dispatches: pack_w, router_mfma, rescue.
//
// Core (r12-verified): block = 4 waves x 64 tokens; wave w owns tile w (16
// tokens, all 64 experts, full K). 16 phases of k=64: X staged 64 rows x 256B
// contiguous/row; W staged ONCE per block (16KB/phase) shared by 4 waves;
// double-buffered (64KB LDS) -> 2 blocks/CU = 8 waves/CU; per-wave counted
// vmcnt(8) + s_barrier, drain only at tail; X ds_reads XOR-swizzled via
// pre-swizzled global source; W LDS reads lane*16 contiguous (conflict-free).
//
// A/B k-mapping: element j of lane l covers k = (l>>4)*8 + j, identical for A
// (in-register split) and B (pack_w) -> permutation-safe.
// C/D layout (m89-verified): col = lane&15, row = (lane>>4)*4 + reg.
//
// Requires ws_size >= 512 KB (cnt @0, list @256, Whi @256K, Wlo @384K).

typedef __attribute__((ext_vector_type(8))) short bf16x8;
typedef __attribute__((ext_vector_type(4))) float f32x4;

#define TOKENS 32768
#define DDIM   1024
#define TAU    1e-3f

#define WS_CNT_OFF   0
#define WS_LIST_OFF  256
#define WS_WHI_OFF   262144
#define WS_WLO_OFF   (262144 + 131072)

#define AS1 __attribute__((address_space(1)))
#define AS3 __attribute__((address_space(3)))

union FragU { bf16x8 v; unsigned int u[4]; };
union FragU4 { bf16x8 v; uint4 q; };

__device__ inline unsigned int pk_bf16(float a, float b) {
    float2 f; f.x = a; f.y = b;
    __hip_bfloat162 h = __float22bfloat162_rn(f);
    union { __hip_bfloat162 h2; unsigned int u; } cv; cv.h2 = h;
    return cv.u;
}
__device__ inline float2 bf2f2(unsigned int u) {
    union { __hip_bfloat162 h2; unsigned int uu; } cv; cv.uu = u;
    return __bfloat1622float2(cv.h2);
}
__device__ inline void merge2(float& v1, int& i1, float& v2, int& i2,
                              float o1, int oi1, float o2, int oi2) {
    const bool b1 = (o1 > v1) || (o1 == v1 && oi1 < i1);
    if (b1) {
        const bool b2 = (v1 > o2) || (v1 == o2 && i1 < oi2);
        v2 = b2 ? v1 : o2;  i2 = b2 ? i1 : oi2;
        v1 = o1;            i1 = oi1;
    } else {
        const bool b2 = (o1 > v2) || (o1 == v2 && oi1 < i2);
        if (b2) { v2 = o1; i2 = oi1; }
    }
}

// ---- kernel 1: pack W into fragment-ordered bf16 hi/lo (+ zero flagCnt) ----
__launch_bounds__(256)
__global__ void pack_w_kernel(const float* __restrict__ W,
                              unsigned int* __restrict__ Whi,
                              unsigned int* __restrict__ Wlo,
                              unsigned int* __restrict__ flagCnt) {
    if (blockIdx.x == 0 && threadIdx.x == 0) *flagCnt = 0u;

    const int idx = blockIdx.x * 256 + threadIdx.x;     // 0..8191 = (s,n,l)
    const int l = idx & 63, n = (idx >> 6) & 3, s = idx >> 8;
    const int e  = n * 16 + (l & 15);
    const int k0 = s * 32 + (l >> 4) * 8;
    const float* p = W + e * DDIM + k0;
    const float4 a = *(const float4*)p;
    const float4 b = *(const float4*)(p + 4);
    const float f[8] = {a.x, a.y, a.z, a.w, b.x, b.y, b.z, b.w};
    unsigned int hu[4], lu[4];
    #pragma unroll
    for (int j = 0; j < 4; ++j) {
        const float x0 = f[2 * j], x1 = f[2 * j + 1];
        const unsigned int h = pk_bf16(x0, x1);
        const float2 hf = bf2f2(h);
        hu[j] = h;
        lu[j] = pk_bf16(x0 - hf.x, x1 - hf.y);
    }
    uint4 hv; hv.x = hu[0]; hv.y = hu[1]; hv.z = hu[2]; hv.w = hu[3];
    uint4 lv; lv.x = lu[0]; lv.y = lu[1]; lv.z = lu[2]; lv.w = lu[3];
    *(uint4*)(Whi + (size_t)idx * 4) = hv;
    *(uint4*)(Wlo + (size_t)idx * 4) = lv;
}

// ---- kernel 2: main MFMA router (cooperative phases, LDS-shared W) ----
__launch_bounds__(256, 2)
__global__ void router_mfma(const float* __restrict__ X,
                            const unsigned int* __restrict__ Whi,
                            const unsigned int* __restrict__ Wlo,
                            const float* __restrict__ Bv,
                            float* __restrict__ Out,
                            unsigned int* __restrict__ flagCnt,
                            int* __restrict__ flagList) {
    // [0,32K): X dbuf (2 x 64 rows x 256B). [32K,64K): W dbuf (2 x (hi 8K + lo 8K)).
    __shared__ __align__(16) char smem[65536];

    const int tid  = threadIdx.x;
    const int w    = tid >> 6;
    const int lane = tid & 63;
    const int rl   = lane & 15;      // A-row (token in tile) / C-col
    const int kg   = lane >> 4;      // k-group
    const int dr   = lane >> 4;      // staging row-within-group
    const int tokBase = blockIdx.x * 64;

    // --- X staging sources (pre-swizzled chunk; dest linear) ---
    const float* xsE = X + (size_t)(tokBase + w * 16 + dr) * DDIM
                         + (((lane & 15) ^ dr) * 4);
    const float* xsO = X + (size_t)(tokBase + w * 16 + dr) * DDIM
                         + (((lane & 15) ^ (dr ^ 4)) * 4);
    const unsigned int* whs = Whi + lane * 4;   // +lane*16B
    const unsigned int* wls = Wlo + lane * 4;

    // --- A-frag swizzled ds_read offsets ---
    const int r7     = rl & 7;
    const int rowoff = w * 4096 + rl * 256;
    const int q0     = ((kg * 2 + 0) ^ r7) * 16;
    const int q1     = ((kg * 2 + 1) ^ r7) * 16;
    const int wlds   = lane * 16;

    f32x4 acc[4] = {f32x4{0,0,0,0}, f32x4{0,0,0,0}, f32x4{0,0,0,0}, f32x4{0,0,0,0}};

#define DMA16(gp, lp) __builtin_amdgcn_global_load_lds((AS1 const void*)(gp), \
                                                       (AS3 void*)(lp), 16, 0, 0)
#define WAITVM(N) asm volatile("s_waitcnt vmcnt(" #N ")" ::: "memory")
#define SB() __builtin_amdgcn_sched_barrier(0)

    auto ISSUE = [&](int p, const float* xE, const float* xO,
                     const unsigned int* wh, const unsigned int* wl) {
        char* xb = smem + ((p & 1) ? 16384 : 0) + w * 4096;
        DMA16(xE,         xb);
        DMA16(xO + 4096,  xb + 1024);
        DMA16(xE + 8192,  xb + 2048);
        DMA16(xO + 12288, xb + 3072);
        char* wb = smem + 32768 + ((p & 1) ? 16384 : 0);
        DMA16(wh + (w * 2 + 0) * 256, wb + (w * 2 + 0) * 1024);
        DMA16(wh + (w * 2 + 1) * 256, wb + (w * 2 + 1) * 1024);
        DMA16(wl + (w * 2 + 0) * 256, wb + 8192 + (w * 2 + 0) * 1024);
        DMA16(wl + (w * 2 + 1) * 256, wb + 8192 + (w * 2 + 1) * 1024);
    };

    auto CONSUME = [&](int p) {
        const char* xb = smem + ((p & 1) ? 16384 : 0);
        const char* wb = smem + 32768 + ((p & 1) ? 16384 : 0);
        #pragma unroll
        for (int sl = 0; sl < 2; ++sl) {
            const float4 x0 = *(const float4*)(xb + rowoff + sl * 128 + q0);
            const float4 x1 = *(const float4*)(xb + rowoff + sl * 128 + q1);
            FragU4 bh[4], bl[4];
            #pragma unroll
            for (int n = 0; n < 4; ++n) {
                bh[n].q = *(const uint4*)(wb + (sl * 4 + n) * 1024 + wlds);
                bl[n].q = *(const uint4*)(wb + 8192 + (sl * 4 + n) * 1024 + wlds);
            }
            FragU ah, al;
            const float fx[8] = {x0.x, x0.y, x0.z, x0.w, x1.x, x1.y, x1.z, x1.w};
            #pragma unroll
            for (int j = 0; j < 4; ++j) {
                const unsigned int h = pk_bf16(fx[2 * j], fx[2 * j + 1]);
                const float2 hf = bf2f2(h);
                ah.u[j] = h;
                al.u[j] = pk_bf16(fx[2 * j] - hf.x, fx[2 * j + 1] - hf.y);
            }
            #pragma unroll
            for (int n = 0; n < 4; ++n) {
                acc[n] = __builtin_amdgcn_mfma_f32_16x16x32_bf16(ah.v, bh[n].v, acc[n], 0, 0, 0);
                acc[n] = __builtin_amdgcn_mfma_f32_16x16x32_bf16(ah.v, bl[n].v, acc[n], 0, 0, 0);
                acc[n] = __builtin_amdgcn_mfma_f32_16x16x32_bf16(al.v, bh[n].v, acc[n], 0, 0, 0);
            }
        }
    };

    // Prologue: phases 0 and 1 in flight (8 DMA each per wave).
    ISSUE(0, xsE, xsO, whs, wls);
    ISSUE(1, xsE + 64, xsO + 64, whs + 2048, wls + 2048);
    const float* xE2 = xsE + 128;
    const float* xO2 = xsO + 128;
    const unsigned int* wh2 = whs + 4096;
    const unsigned int* wl2 = wls + 4096;

    #pragma unroll 1
    for (int p = 0; p < 15; ++p) {
        WAITVM(8);                       // own phase-p DMAs done; p+1 in flight
        __builtin_amdgcn_s_barrier();    // -> block-wide: phase p fully in LDS
        SB();
        CONSUME(p);
        SB();
        __builtin_amdgcn_s_barrier();    // all reads of slot (p&1) done
        if (p < 14) {
            ISSUE(p + 2, xE2, xO2, wh2, wl2);
            xE2 += 64; xO2 += 64; wh2 += 2048; wl2 += 2048;
        }
    }
    WAITVM(0);
    __builtin_amdgcn_s_barrier();
    SB();
    CONSUME(15);

#undef DMA16
#undef WAITVM
#undef SB

    // ---- wave-private epilogue: bias + top-2 + softmax + write (tile w) ----
    float bv[4];
    #pragma unroll
    for (int n = 0; n < 4; ++n) bv[n] = Bv[n * 16 + rl];

    #pragma unroll
    for (int r = 0; r < 4; ++r) {
        float v[4];
        #pragma unroll
        for (int n = 0; n < 4; ++n) v[n] = acc[n][r] + bv[n];

        float v1 = -INFINITY, v2 = -INFINITY;
        int i1 = 0x7fffffff, i2 = 0x7fffffff;
        #pragma unroll
        for (int n = 0; n < 4; ++n) {
            const float val = v[n];
            const int   e   = n * 16 + rl;
            if (val > v1 || (val == v1 && e < i1)) { v2 = v1; i2 = i1; v1 = val; i1 = e; }
            else if (val > v2 || (val == v2 && e < i2)) { v2 = val; i2 = e; }
        }
        #pragma unroll
        for (int st = 1; st <= 8; st <<= 1) {
            const float o1 = __shfl_xor(v1, st); const int oi1 = __shfl_xor(i1, st);
            const float o2 = __shfl_xor(v2, st); const int oi2 = __shfl_xor(i2, st);
            merge2(v1, i1, v2, i2, o1, oi1, o2, oi2);
        }
        int cnt = 0;
        #pragma unroll
        for (int n = 0; n < 4; ++n) cnt += (v[n] > v2 - TAU) ? 1 : 0;
        cnt += __shfl_xor(cnt, 1);
        cnt += __shfl_xor(cnt, 2);
        cnt += __shfl_xor(cnt, 4);
        cnt += __shfl_xor(cnt, 8);

        const int T = tokBase + w * 16 + kg * 4 + r;
        if (rl == 0 && cnt > 2) {
            const unsigned int pos = atomicAdd(flagCnt, 1u);
            if (pos < TOKENS) flagList[pos] = T;
        }
        const float ex = expf(v2 - v1);      // <= 1
        const float w1 = 1.f / (1.f + ex);
        const float w2 = ex * w1;
        const int e0 = rl * 4;
        float4 o;
        o.x = (e0 + 0 == i1) ? w1 : ((e0 + 0 == i2) ? w2 : 0.f);
        o.y = (e0 + 1 == i1) ? w1 : ((e0 + 1 == i2) ? w2 : 0.f);
        o.z = (e0 + 2 == i1) ? w1 : ((e0 + 2 == i2) ? w2 : 0.f);
        o.w = (e0 + 3 == i1) ? w1 : ((e0 + 3 == i2) ? w2 : 0.f);
        *(float4*)(Out + (size_t)T * 64 + e0) = o;
    }
}

// ---- kernel 3: exact fp32 rescue for near-tie tokens ----
__launch_bounds__(64)
__global__ void rescue_kernel(const float* __restrict__ X,
                              const float* __restrict__ W,
                              const float* __restrict__ Bv,
                              float* __restrict__ Out,
                              const unsigned int* __restrict__ flagCnt,
                              const int* __restrict__ flagList) {
    __shared__ float sx[DDIM];
    const int lane = threadIdx.x;
    unsigned int n = *flagCnt;
    if (n > TOKENS) n = TOKENS;
    for (unsigned int i = blockIdx.x; i < n; i += gridDim.x) {
        const int t = flagList[i];
        __syncthreads();
        #pragma unroll
        for (int k = 0; k < 4; ++k)
            ((float4*)sx)[lane + 64 * k] =
                ((const float4*)(X + (size_t)t * DDIM))[lane + 64 * k];
        __syncthreads();
        float acc = Bv[lane];
        const float* wr = W + (size_t)lane * DDIM;
        #pragma unroll 4
        for (int d = 0; d < DDIM; d += 4) {
            const float4 wv = *(const float4*)(wr + d);
            acc = fmaf(sx[d + 0], wv.x, acc);
            acc = fmaf(sx[d + 1], wv.y, acc);
            acc = fmaf(sx[d + 2], wv.z, acc);
            acc = fmaf(sx[d + 3], wv.w, acc);
        }
        float v1 = acc, v2 = -INFINITY;
        int i1 = lane, i2 = 0x7fffffff;
        #pragma unroll
        for (int st = 1; st <= 32; st <<= 1) {
            const float o1 = __shfl_xor(v1, st); const int oi1 = __shfl_xor(i1, st);
            const float o2 = __shfl_xor(v2, st); const int oi2 = __shfl_xor(i2, st);
            merge2(v1, i1, v2, i2, o1, oi1, o2, oi2);
        }
        const float ex = expf(v2 - v1);
        const float w1 = 1.f / (1.f + ex);
        const float w2 = ex * w1;
        Out[(size_t)t * 64 + lane] = (lane == i1) ? w1 : ((lane == i2) ? w2 : 0.f);
    }
}

extern "C" void kernel_launch(void* const* d_in, const int* in_sizes, int n_in,
                              void* d_out, int out_size, void* d_ws, size_t ws_size,
                              hipStream_t stream) {
    const float* X  = (const float*)d_in[0];   // [32768, 1024]
    const float* W  = (const float*)d_in[1];   // [64, 1024]
    const float* Bv = (const float*)d_in[2];   // [64]
    float* Out = (float*)d_out;                // [32768, 64]

    unsigned char* ws = (unsigned char*)d_ws;
    unsigned int* cnt  = (unsigned int*)(ws + WS_CNT_OFF);
    int*          list = (int*)(ws + WS_LIST_OFF);
    unsigned int* Whi  = (unsigned int*)(ws + WS_WHI_OFF);
    unsigned int* Wlo  = (unsigned int*)(ws + WS_WLO_OFF);

    hipLaunchKernelGGL(pack_w_kernel, dim3(32), dim3(256), 0, stream, W, Whi, Wlo, cnt);
    hipLaunchKernelGGL(router_mfma, dim3(TOKENS / 64), dim3(256), 0, stream,
                       X, Whi, Wlo, Bv, Out, cnt, list);
    hipLaunchKernelGGL(rescue_kernel, dim3(128), dim3(64), 0, stream,
                       X, W, Bv, Out, cnt, list);
}